// Round 10
// baseline (632.634 us; speedup 1.0000x reference)
//
#include <hip/hip_runtime.h>
#include <hip/hip_bf16.h>
#include <math.h>

#define HID     2560
#define D_INNER 8192
#define NG      32
#define D_SSM   4096
#define KCONV   4
#define HD      128
#define DS      64
#define LSEQ    1024
#define LC      64
#define NC      (LSEQ / LC)
#define NZ      4224          // z(4096) + dt(32) + D(32) + pad(64)
#define NBIG    12416         // qkv(8192) + NZ
#define EPS_RMS 1e-6f

// ---- gemm_big256 deep-pipeline params ----
#define BKT       32          // K per tile
#define NKT       240         // K' = 3*2560 -> 240 tiles of 32
#define GB_BLOCKS 196         // 49 n-tiles * 4 m-tiles

typedef short bf16x8 __attribute__((ext_vector_type(8)));
typedef float f32x4 __attribute__((ext_vector_type(4)));
typedef float f32x16 __attribute__((ext_vector_type(16)));

__device__ __forceinline__ float siluf(float x) { return x / (1.f + expf(-x)); }

__device__ __forceinline__ unsigned short f2bf(float x) {
    __hip_bfloat16 b = __float2bfloat16(x);
    return *reinterpret_cast<unsigned short*>(&b);
}
__device__ __forceinline__ float bf2f(unsigned short u) {
    union { unsigned int i; float f; } v;
    v.i = ((unsigned int)u) << 16;
    return v.f;
}

__device__ __forceinline__ void async16(const ushort* g, ushort* l) {
    __builtin_amdgcn_global_load_lds(
        (const __attribute__((address_space(1))) unsigned int*)g,
        (__attribute__((address_space(3))) unsigned int*)l, 16, 0, 0);
}

// counted-vmcnt gate: drain own ds_reads (lgkmcnt 0), leave VM staging loads
// in flight across the raw barrier (T4). Compile-time VM only.
template<int VM>
__device__ __forceinline__ void gate_barrier() {
    asm volatile("s_waitcnt vmcnt(%0) lgkmcnt(0)" :: "n"(VM) : "memory");
    __builtin_amdgcn_s_barrier();
    asm volatile("" ::: "memory");
}

__device__ __forceinline__ void cvt4(const float4& v, ushort4& h, ushort4& l) {
    h.x = f2bf(v.x); l.x = f2bf(v.x - bf2f(h.x));
    h.y = f2bf(v.y); l.y = f2bf(v.y - bf2f(h.y));
    h.z = f2bf(v.z); l.z = f2bf(v.z - bf2f(h.z));
    h.w = f2bf(v.w); l.w = f2bf(v.w - bf2f(h.w));
}

// ---------------- fused input-plane conversion (5 launches -> 1) -----------
#define N4_HS   (LSEQ * HID / 4)
#define N4_QKV  (D_INNER * HID / 4)
#define N4_Z    (D_SSM * HID / 4)
#define N4_BA   (NG * HID / 4)
__global__ __launch_bounds__(256)
void split_cvt_all(const float4* __restrict__ hs, const float4* __restrict__ wqkv,
                   const float4* __restrict__ wz, const float4* __restrict__ wb,
                   const float4* __restrict__ wa,
                   ushort4* __restrict__ hsH4, ushort4* __restrict__ hsL4,
                   ushort4* __restrict__ WH4, ushort4* __restrict__ WL4) {
    int i = blockIdx.x * 256 + threadIdx.x;
    const float4* src; ushort4* dh; ushort4* dl; int j;
    if (i < N4_HS)                          { j = i;                       src = hs;   dh = hsH4; dl = hsL4; }
    else if ((j = i - N4_HS) < N4_QKV)      {                              src = wqkv; dh = WH4;  dl = WL4; }
    else if ((j -= N4_QKV) < N4_Z)          { src = wz; dh = WH4 + N4_QKV;            dl = WL4 + N4_QKV; }
    else if ((j -= N4_Z) < N4_BA)           { src = wb; dh = WH4 + N4_QKV + N4_Z;     dl = WL4 + N4_QKV + N4_Z; }
    else                                    { j -= N4_BA;
                                              src = wa; dh = WH4 + N4_QKV + N4_Z + N4_BA;
                                                        dl = WL4 + N4_QKV + N4_Z + N4_BA; }
    float4 v = src[j];
    ushort4 h, l; cvt4(v, h, l);
    dh[j] = h; dl[j] = l;
}

// ---------------- big GEMM: 256x256 tile, 4 waves x (128x128), 32x32x16 -----
// v2 (round 10): LDS-read-BW was co-critical with MFMA in the 8-wave 2x4
// layout (96KB reads/kt, 4x A amplification). 4 waves in a 2x2 grid with
// square 128x128 wave-tiles cut LDS reads to 64KB/kt (2x amplification on
// both operands), and 32x32x16 MFMA runs 13% more FLOP/cycle than 16x16x32
// (m06). Ring, gates, staging swizzle, XCD swizzle unchanged (vmcnt counts
// scale x2: 8 loads/stage). C/D layout per m74/m101:
//   col = lane&31, row = (reg&3) + 8*(reg>>2) + 4*(lane>>5).
// A/B operand: row/col = lane&31, k = (lane>>5)*8 (32-row analog of the
// proven 16-row mapping).
__global__ __launch_bounds__(256, 1)
void gemm_big256(const ushort* __restrict__ Ah, const ushort* __restrict__ Al,
                 const ushort* __restrict__ Bh, const ushort* __restrict__ Bl,
                 float* __restrict__ xBC, float* __restrict__ zq)
{
    __shared__ ushort lds[4][2][256][32];

    const int tid  = threadIdx.x;
    const int lane = tid & 63, wv = tid >> 6;       // wv 0..3

    int id = blockIdx.x;
    const int qx = GB_BLOCKS / 8, rx = GB_BLOCKS % 8;       // 24, 4
    int xcd = id & 7, lid = id >> 3;
    int sw  = (xcd < rx) ? (xcd * (qx + 1) + lid)
                         : (rx * (qx + 1) + (xcd - rx) * qx + lid);
    const int m0 = (sw & 3) << 8;
    const int n0 = (sw >> 2) << 8;

    // stage-side: per wave 4 row-chunks (16 rows each) of A and of B.
    const int rb  = (wv << 4) + (lane >> 2);                 // row in 64-group
    const int csw = (((lane & 3) ^ ((lane >> 3) & 3)) << 3); // src k-chunk (swz)

    auto stage = [&](int kt, int slot) {
        int third = kt / 80;
        int kk = (kt - third * 80) * BKT;
        const ushort* Ap = (third == 2) ? Al : Ah;   // [Ah, Ah, Al]
        const ushort* Bp = (third == 1) ? Bl : Bh;   // [Bh, Bl, Bh]
        int cs = kk + csw;
        ushort* dA = &lds[slot][0][wv << 4][0];      // wave-uniform base
        ushort* dB = &lds[slot][1][wv << 4][0];
        #pragma unroll
        for (int j = 0; j < 4; j++) {
            int ar = m0 + j * 64 + rb;
            int br = n0 + j * 64 + rb; if (br > NBIG - 1) br = NBIG - 1;
            async16(Ap + (size_t)ar * HID + cs, dA + j * 64 * 32);
            async16(Bp + (size_t)br * HID + cs, dB + j * 64 * 32);
        }
    };

    // compute-side: 2x2 waves, per-wave 128x128, 4x4 frags of 32x32.
    const int wm  = (wv >> 1) << 7;                 // 0 / 128
    const int wn  = (wv & 1) << 7;                  // 0 / 128
    const int r31 = lane & 31;
    const int khi = lane >> 5;                      // 0/1 -> k = khi*8
    const int cxr = (lane >> 1) & 3;                // read-side chunk XOR

    f32x16 acc[4][4];
    #pragma unroll
    for (int i = 0; i < 4; i++)
        #pragma unroll
        for (int j = 0; j < 4; j++)
            acc[i][j] = (f32x16){0.f,0.f,0.f,0.f,0.f,0.f,0.f,0.f,
                                 0.f,0.f,0.f,0.f,0.f,0.f,0.f,0.f};

    auto compute = [&](int slot) {
        const ushort* sA = &lds[slot][0][0][0];
        const ushort* sB = &lds[slot][1][0][0];
        bf16x8 a[4][2], b[4][2];
        #pragma unroll
        for (int f = 0; f < 4; f++)
            #pragma unroll
            for (int k0 = 0; k0 < 2; k0++) {
                int ph = ((k0 * 2 + khi) ^ cxr) << 3;
                a[f][k0] = *(const bf16x8*)&sA[(wm + f * 32 + r31) * 32 + ph];
                b[f][k0] = *(const bf16x8*)&sB[(wn + f * 32 + r31) * 32 + ph];
            }
        __builtin_amdgcn_s_setprio(1);
        #pragma unroll
        for (int fm = 0; fm < 4; fm++)
            #pragma unroll
            for (int fn = 0; fn < 4; fn++)
                #pragma unroll
                for (int k0 = 0; k0 < 2; k0++)
                    acc[fm][fn] = __builtin_amdgcn_mfma_f32_32x32x16_bf16(
                        a[fm][k0], b[fn][k0], acc[fm][fn], 0, 0, 0);
        __builtin_amdgcn_s_setprio(0);
    };

    // prologue: prefetch depth 3 (24 loads/wave in flight)
    stage(0, 0); stage(1, 1); stage(2, 2);

    #pragma unroll 4
    for (int kt = 0; kt < NKT - 4; kt++) {
        gate_barrier<16>();                 // tile kt landed (24 -> 16)
        stage(kt + 3, (kt + 3) & 3);
        compute(kt & 3);
    }
    gate_barrier<16>(); stage(239, 3); compute(0);   // kt = 236
    gate_barrier<16>(); compute(1);                  // kt = 237
    gate_barrier<8>();  compute(2);                  // kt = 238
    gate_barrier<0>();  compute(3);                  // kt = 239

    // ---- epilogue: 32x32 C/D layout, col split xBC/zq, pad cols dropped ----
    const int rbase = (lane >> 5) << 2;     // 4*(lane>>5)
    #pragma unroll
    for (int fm = 0; fm < 4; fm++) {
        #pragma unroll
        for (int fn = 0; fn < 4; fn++) {
            int col = n0 + wn + fn * 32 + r31;
            if (col < 8192) {
                #pragma unroll
                for (int reg = 0; reg < 16; reg++) {
                    int row = m0 + wm + fm * 32 + (reg & 3) + 8 * (reg >> 2) + rbase;
                    xBC[(size_t)row * 8192 + col] = acc[fm][fn][reg];
                }
            } else if (col < NBIG) {
                #pragma unroll
                for (int reg = 0; reg < 16; reg++) {
                    int row = m0 + wm + fm * 32 + (reg & 3) + 8 * (reg >> 2) + rbase;
                    zq[(size_t)row * NZ + (col - 8192)] = acc[fm][fn][reg];
                }
            }
        }
    }
}

// ---------------- phase-2 fused: conv+SiLU | W_out cvt | dt_scan ------------
#define CONV_BLKS 2048
#define WOUT_BLKS 2560
#define DT_BLKS   NG
__global__ __launch_bounds__(1024)
void phase2_fused(const float4* __restrict__ xBC4, const float4* __restrict__ cw4,
                  float4* __restrict__ xconv4,
                  const float4* __restrict__ Wout_src,
                  ushort4* __restrict__ WoH4, ushort4* __restrict__ WoL4,
                  const float* __restrict__ zq,
                  const float* __restrict__ A_log, const float* __restrict__ dt_bias,
                  float* __restrict__ dt_soft, float* __restrict__ Sbuf,
                  float* __restrict__ Ebuf) {
    const int tid = threadIdx.x;
    if (blockIdx.x < CONV_BLKS) {
        int idx4 = blockIdx.x * 1024 + tid;
        int t  = idx4 >> 11;
        int c4 = idx4 & 2047;
        float4 w0 = cw4[c4 * 4 + 0], w1 = cw4[c4 * 4 + 1];
        float4 w2 = cw4[c4 * 4 + 2], w3 = cw4[c4 * 4 + 3];
        float4 acc = {0.f, 0.f, 0.f, 0.f};
        #pragma unroll
        for (int k = 0; k < KCONV; k++) {
            int tt = t - (KCONV - 1) + k;
            if (tt >= 0) {
                float4 x = xBC4[(size_t)tt * 2048 + c4];
                float t0 = (k == 0) ? w0.x : (k == 1) ? w0.y : (k == 2) ? w0.z : w0.w;
                float t1 = (k == 0) ? w1.x : (k == 1) ? w1.y : (k == 2) ? w1.z : w1.w;
                float t2 = (k == 0) ? w2.x : (k == 1) ? w2.y : (k == 2) ? w2.z : w2.w;
                float t3 = (k == 0) ? w3.x : (k == 1) ? w3.y : (k == 2) ? w3.z : w3.w;
                acc.x += x.x * t0; acc.y += x.y * t1;
                acc.z += x.z * t2; acc.w += x.w * t3;
            }
        }
        acc.x = siluf(acc.x); acc.y = siluf(acc.y);
        acc.z = siluf(acc.z); acc.w = siluf(acc.w);
        xconv4[idx4] = acc;
    } else if (blockIdx.x < CONV_BLKS + WOUT_BLKS) {
        int i = (blockIdx.x - CONV_BLKS) * 1024 + tid;
        float4 v = Wout_src[i];
        ushort4 h, l; cvt4(v, h, l);
        WoH4[i] = h; WoL4[i] = l;
    } else {
        const int g = blockIdx.x - (CONV_BLKS + WOUT_BLKS);
        const int t = tid;
        __shared__ float buf0[LSEQ], buf1[LSEQ];
        float dtr = zq[(size_t)t * NZ + D_SSM + g] + dt_bias[g];
        float dt = (dtr > 20.f) ? dtr : log1pf(expf(dtr));
        dt_soft[g * LSEQ + t] = dt;
        buf0[t] = dt;
        __syncthreads();
        float* src = buf0; float* dst = buf1;
        for (int off = 1; off < LSEQ; off <<= 1) {
            float v = src[t];
            if (t >= off) v += src[t - off];
            dst[t] = v;
            __syncthreads();
            float* tmp = src; src = dst; dst = tmp;
        }
        float A = -expf(A_log[g]);
        float S = A * src[t];
        Sbuf[g * LSEQ + t] = S;
        if ((t & (LC - 1)) == LC - 1) Ebuf[g * NC + (t >> 6)] = S;
    }
}

// ---------------- out GEMM: 256^2 tiles, split-K x6, DIRECT partial stores --
__global__ __launch_bounds__(512, 2)
void gemm_out_sk256(const ushort* __restrict__ Ah, const ushort* __restrict__ Al,
                    const ushort* __restrict__ Bh, const ushort* __restrict__ Bl,
                    float* __restrict__ P)
{
    constexpr int LDA = D_SSM;
    constexpr int KT3 = 128;

    __shared__ ushort lds[4][2][256][32];

    const int tid  = threadIdx.x;
    const int lane = tid & 63, wv = tid >> 6;

    const int bid = blockIdx.x;
    const int wid = (bid & 7) * 30 + (bid >> 3);
    const int m   = wid & 3;
    const int q   = wid >> 2;
    const int n   = q % 10;
    const int kz  = q / 10;
    const int m0  = m << 8, n0 = n << 8;
    const int kt0 = kz * 64;

    const int rb  = (wv << 4) + (lane >> 2);
    const int csw = (((lane & 3) ^ ((lane >> 3) & 3)) << 3);
    const int wm  = (wv >> 2) << 7;
    const int wn  = (wv & 3) << 6;
    const int fr  = lane & 15;
    const int ckr = (((lane >> 4) ^ ((lane >> 1) & 3)) << 3);
    const int rq  = (lane >> 4) << 2;

    auto stage = [&](int kt, int slot) {
        int third = kt / KT3;
        int kk = (kt - third * KT3) * BKT;
        const ushort* Ap = (third == 2) ? Al : Ah;
        const ushort* Bp = (third == 1) ? Bl : Bh;
        int cs = kk + csw;
        ushort* dA = &lds[slot][0][wv << 4][0];
        ushort* dB = &lds[slot][1][wv << 4][0];
        async16(Ap + (size_t)(m0 + rb) * LDA + cs, dA);
        async16(Ap + (size_t)(m0 + 128 + rb) * LDA + cs, dA + 128 * 32);
        async16(Bp + (size_t)(n0 + rb) * LDA + cs, dB);
        async16(Bp + (size_t)(n0 + 128 + rb) * LDA + cs, dB + 128 * 32);
    };

    f32x4 acc[8][4];
    #pragma unroll
    for (int i = 0; i < 8; i++)
        #pragma unroll
        for (int j = 0; j < 4; j++) acc[i][j] = (f32x4){0.f, 0.f, 0.f, 0.f};

    auto compute = [&](int slot) {
        const ushort* sA = &lds[slot][0][0][0];
        const ushort* sB = &lds[slot][1][0][0];
        bf16x8 a[8], b[4];
        #pragma unroll
        for (int mt = 0; mt < 8; mt++)
            a[mt] = *(const bf16x8*)&sA[(wm + mt * 16 + fr) * 32 + ckr];
        #pragma unroll
        for (int nt = 0; nt < 4; nt++)
            b[nt] = *(const bf16x8*)&sB[(wn + nt * 16 + fr) * 32 + ckr];
        __builtin_amdgcn_s_setprio(1);
        #pragma unroll
        for (int mt = 0; mt < 8; mt++)
            #pragma unroll
            for (int nt = 0; nt < 4; nt++)
                acc[mt][nt] = __builtin_amdgcn_mfma_f32_16x16x32_bf16(
                    a[mt], b[nt], acc[mt][nt], 0, 0, 0);
        __builtin_amdgcn_s_setprio(0);
    };

    stage(kt0 + 0, 0); stage(kt0 + 1, 1); stage(kt0 + 2, 2);
    #pragma unroll 4
    for (int i = 0; i < 60; i++) {
        gate_barrier<8>();
        stage(kt0 + i + 3, (i + 3) & 3);
        compute(i & 3);
    }
    gate_barrier<8>(); stage(kt0 + 63, 63 & 3); compute(60 & 3);
    gate_barrier<8>(); compute(61 & 3);
    gate_barrier<4>(); compute(62 & 3);
    gate_barrier<0>(); compute(63 & 3);

    float* dst = P + (size_t)kz * LSEQ * HID;
    #pragma unroll
    for (int mt = 0; mt < 8; mt++) {
        int row = m0 + wm + mt * 16 + rq;
        #pragma unroll
        for (int nt = 0; nt < 4; nt++) {
            int col = n0 + wn + nt * 16 + fr;
            #pragma unroll
            for (int r = 0; r < 4; r++)
                dst[(size_t)(row + r) * HID + col] = acc[mt][nt][r];
        }
    }
}

// ---------------- reduce the 6 split-K partials into out ----------------
__global__ __launch_bounds__(256)
void reduce6(const float4* __restrict__ P4, float4* __restrict__ out4) {
    const int N4 = LSEQ * HID / 4;       // 655,360
    int i = blockIdx.x * 256 + threadIdx.x;
    float4 s = P4[i];
    #pragma unroll
    for (int kz = 1; kz < 6; kz++) {
        float4 p = P4[(size_t)kz * N4 + i];
        s.x += p.x; s.y += p.y; s.z += p.z; s.w += p.w;
    }
    out4[i] = s;
}

// ---------------- S2: chunk states ----------------
__global__ __launch_bounds__(256)
void chunk_state(const float* __restrict__ xc, const float* __restrict__ dt_soft,
                 const float* __restrict__ Sbuf, const float* __restrict__ Ebuf,
                 float* __restrict__ Sc) {
    const int g = blockIdx.x, c = blockIdx.y;
    const int tid = threadIdx.x;
    const int t0 = c * LC;
    __shared__ __align__(16) float wB[LC][DS];
    __shared__ float Xs[LC][HD];
    __shared__ float sw[LC];

    if (tid < LC) {
        float Ec = Ebuf[g * NC + c];
        sw[tid] = expf(Ec - Sbuf[g * LSEQ + t0 + tid]) * dt_soft[g * LSEQ + t0 + tid];
    }
    __syncthreads();
    for (int i = tid; i < LC * DS; i += 256) {
        int r = i >> 6, s = i & 63;
        wB[r][s] = sw[r] * xc[(size_t)(t0 + r) * D_INNER + D_SSM + g * DS + s];
    }
    for (int i = tid; i < LC * HD; i += 256) {
        int r = i >> 7, h = i & 127;
        Xs[r][h] = xc[(size_t)(t0 + r) * D_INNER + g * HD + h];
    }
    __syncthreads();

    const int h = tid & 127, sh = (tid >> 7) * 32;
    float acc[32];
    #pragma unroll
    for (int j = 0; j < 32; j++) acc[j] = 0.f;
    for (int r = 0; r < LC; r++) {
        float xv = Xs[r][h];
        const float4* wrow = (const float4*)&wB[r][sh];
        #pragma unroll
        for (int q = 0; q < 8; q++) {
            float4 w4 = wrow[q];
            acc[4*q+0] += w4.x * xv;
            acc[4*q+1] += w4.y * xv;
            acc[4*q+2] += w4.z * xv;
            acc[4*q+3] += w4.w * xv;
        }
    }
    float* out = Sc + (size_t)(g * NC + c) * DS * HD;
    #pragma unroll
    for (int j = 0; j < 32; j++) out[(size_t)(sh + j) * HD + h] = acc[j];
}

// ---------------- S3: prefix over chunks ----------------
__global__ __launch_bounds__(256)
void chunk_prefix(const float* __restrict__ Sc, const float* __restrict__ Ebuf,
                  float* __restrict__ Hbuf) {
    const int g = blockIdx.y;
    const int e = blockIdx.x * 256 + threadIdx.x;
    float H = 0.f, Eprev = 0.f;
    for (int c = 0; c < NC; c++) {
        size_t base = (size_t)(g * NC + c) * DS * HD;
        Hbuf[base + e] = H;
        float Ec = Ebuf[g * NC + c];
        H = expf(Ec - Eprev) * H + Sc[base + e];
        Eprev = Ec;
    }
}

// ---------------- S4: per-chunk output + RMSNorm + SiLU(z), emits yg hi/lo ----
__global__ __launch_bounds__(256)
void chunk_output(const float* __restrict__ xc, const float* __restrict__ dt_soft,
                  const float* __restrict__ Sbuf, const float* __restrict__ Ebuf,
                  const float* __restrict__ Hbuf,
                  const float* __restrict__ zq, const float* __restrict__ norm_w,
                  ushort* __restrict__ ygH, ushort* __restrict__ ygL) {
    const int g = blockIdx.x, c = blockIdx.y;
    const int tid = threadIdx.x;
    const int t0 = c * LC;

    __shared__ __align__(16) float smem[4096 + 4096 + 8192];
    float* CT = smem;
    float* BW = smem + 4096;
    float* Xs = smem + 8192;
    float* red = smem;
    float* sscale = smem + 256;

    for (int i = tid; i < LC * DS; i += 256) {
        int t = i >> 6, s = i & 63;
        CT[s * LC + t] = xc[(size_t)(t0 + t) * D_INNER + D_SSM + NG * DS + g * DS + s];
        BW[t * DS + s] = xc[(size_t)(t0 + t) * D_INNER + D_SSM + g * DS + s];
    }
    for (int i = tid; i < LC * HD; i += 256) {
        int t = i >> 7, h = i & 127;
        Xs[t * HD + h] = xc[(size_t)(t0 + t) * D_INNER + g * HD + h];
    }
    __syncthreads();

    {
        const int t = tid & 63, tau0 = tid >> 6;
        float Greg[16];
        #pragma unroll
        for (int k = 0; k < 16; k++) Greg[k] = 0.f;
        for (int s = 0; s < DS; s++) {
            float cv = CT[s * LC + t];
            #pragma unroll
            for (int k = 0; k < 16; k++) Greg[k] += cv * BW[(tau0 + 4 * k) * DS + s];
        }
        __syncthreads();
        float St = Sbuf[g * LSEQ + t0 + t];
        #pragma unroll
        for (int k = 0; k < 16; k++) {
            int tau = tau0 + 4 * k;
            float w = 0.f;
            if (tau <= t)
                w = expf(St - Sbuf[g * LSEQ + t0 + tau]) *
                    dt_soft[g * LSEQ + t0 + tau] * Greg[k];
            BW[tau * LC + t] = w;
        }
    }
    __syncthreads();

    const int h = tid & 127, tb = (tid >> 7) * 32;
    float y[32], T[32];
    #pragma unroll
    for (int j = 0; j < 32; j++) { y[j] = 0.f; T[j] = 0.f; }

    for (int tau = 0; tau < LC; tau++) {
        float xv = Xs[tau * HD + h];
        const float4* wrow = (const float4*)&BW[tau * LC + tb];
        #pragma unroll
        for (int q = 0; q < 8; q++) {
            float4 w4 = wrow[q];
            y[4*q+0] += w4.x * xv;
            y[4*q+1] += w4.y * xv;
            y[4*q+2] += w4.z * xv;
            y[4*q+3] += w4.w * xv;
        }
    }
    {
        const float* Hg = Hbuf + (size_t)(g * NC + c) * DS * HD;
        for (int s = 0; s < DS; s++) {
            float Hv = Hg[(size_t)s * HD + h];
            const float* crow = &CT[s * LC + tb];
            #pragma unroll
            for (int j = 0; j < 32; j++) T[j] += crow[j] * Hv;
        }
    }
    float Eprev = (c > 0) ? Ebuf[g * NC + c - 1] : 0.f;
    #pragma unroll
    for (int j = 0; j < 32; j++) {
        int t = tb + j;
        float St = Sbuf[g * LSEQ + t0 + t];
        float Dv = zq[(size_t)(t0 + t) * NZ + D_SSM + NG + g];
        y[j] += expf(St - Eprev) * T[j] + Dv * Xs[t * HD + h];
    }
    __syncthreads();
    #pragma unroll
    for (int j = 0; j < 32; j++) Xs[(tb + j) * HD + h] = y[j];
    __syncthreads();

    {
        int t = tid >> 2, q = tid & 3;
        float p = 0.f;
        for (int i = 0; i < 32; i++) {
            float v = Xs[t * HD + q * 32 + i];
            p += v * v;
        }
        red[t * 4 + q] = p;
    }
    __syncthreads();
    if (tid < LC) {
        float s2 = red[tid*4] + red[tid*4+1] + red[tid*4+2] + red[tid*4+3];
        sscale[tid] = rsqrtf(s2 * (1.f / HD) + EPS_RMS);
    }
    __syncthreads();

    float nw = norm_w[h];
    #pragma unroll
    for (int j = 0; j < 32; j++) {
        int t = tb + j;
        float zv = zq[(size_t)(t0 + t) * NZ + g * HD + h];
        size_t idx = (size_t)(t0 + t) * D_SSM + g * HD + h;
        float val = y[j] * sscale[t] * nw * siluf(zv);
        unsigned short hb = f2bf(val);
        ygH[idx] = hb;
        ygL[idx] = f2bf(val - bf2f(hb));
    }
}

extern "C" void kernel_launch(void* const* d_in, const int* in_sizes, int n_in,
                              void* d_out, int out_size, void* d_ws, size_t ws_size,
                              hipStream_t stream) {
    const float* hs      = (const float*)d_in[0];
    const float* W_qkv   = (const float*)d_in[1];
    const float* W_z     = (const float*)d_in[2];
    const float* W_a     = (const float*)d_in[3];
    const float* W_b     = (const float*)d_in[4];
    const float* conv_w  = (const float*)d_in[5];
    const float* W_out   = (const float*)d_in[6];
    const float* norm_w  = (const float*)d_in[7];
    const float* A_log   = (const float*)d_in[8];
    const float* dt_bias = (const float*)d_in[9];
    float* out = (float*)d_out;

    float* ws      = (float*)d_ws;
    float* xBC     = ws;                                   // 8,388,608 f
    float* zq      = xBC + (size_t)LSEQ * D_INNER;         // 4,325,376 f
    float* dt_soft = zq + (size_t)LSEQ * NZ;               // 32768 f
    float* Sbuf    = dt_soft + (size_t)NG * LSEQ;          // 32768 f
    float* Ebuf    = Sbuf + (size_t)NG * LSEQ;             // 512 f
    ushort* hsH    = (ushort*)(Ebuf + 512);                // 2,621,440 us
    ushort* hsL    = hsH + (size_t)LSEQ * HID;
    ushort* WH     = hsL + (size_t)LSEQ * HID;             // NBIG*HID = 31,784,960 us
    ushort* WL     = WH + (size_t)NBIG * HID;
    // phase-2 overlay on WH/WL region (dead after gemm_big256):
    float* xconv   = (float*)WH;                           // 8,388,608 f
    float* Sc      = xconv + (size_t)LSEQ * D_INNER;       // 4,194,304 f
    float* Hbuf    = Sc + (size_t)NG * NC * DS * HD;       // 4,194,304 f
    ushort* ygH    = (ushort*)(Hbuf + (size_t)NG * NC * DS * HD);  // 4,194,304 us
    ushort* ygL    = ygH + (size_t)LSEQ * D_SSM;
    ushort* WoH    = ygL + (size_t)LSEQ * D_SSM;           // 10,485,760 us
    ushort* WoL    = WoH + (size_t)HID * D_SSM;
    // phase-3 overlay: split-K partials [6][1024][2560] f32 (15.7M f) in
    // xconv+Sc+Hbuf (16.8M f) — dead after chunk_output (round-6 audit).
    float* part    = xconv;

    // 1) all input planes in one kernel
    split_cvt_all<<<dim3(33440), dim3(256), 0, stream>>>(
        (const float4*)hs, (const float4*)W_qkv, (const float4*)W_z,
        (const float4*)W_b, (const float4*)W_a,
        (ushort4*)hsH, (ushort4*)hsL, (ushort4*)WH, (ushort4*)WL);

    // 2) merged projection GEMM: 196 blocks, 4-wave square-tile v2
    gemm_big256<<<dim3(GB_BLOCKS), dim3(256), 0, stream>>>(
        hsH, hsL, WH, WL, xBC, zq);

    // 3) conv+SiLU | W_out planes | dt-scan
    phase2_fused<<<dim3(CONV_BLKS + WOUT_BLKS + DT_BLKS), dim3(1024), 0, stream>>>(
        (const float4*)xBC, (const float4*)conv_w, (float4*)xconv,
        (const float4*)W_out, (ushort4*)WoH, (ushort4*)WoL,
        zq, A_log, dt_bias, dt_soft, Sbuf, Ebuf);

    dim3 blk(256);
    chunk_state<<<dim3(NG, NC), blk, 0, stream>>>(xconv, dt_soft, Sbuf, Ebuf, Sc);
    chunk_prefix<<<dim3(DS * HD / 256, NG), blk, 0, stream>>>(Sc, Ebuf, Hbuf);
    chunk_output<<<dim3(NG, NC), blk, 0, stream>>>(xconv, dt_soft, Sbuf, Ebuf,
                                                   Hbuf, zq, norm_w, ygH, ygL);

    // out = yg @ W_out^T: direct partial stores (no atomics), then reduce.
    gemm_out_sk256<<<dim3(240), dim3(512), 0, stream>>>(
        ygH, ygL, WoH, WoL, part);
    reduce6<<<dim3(LSEQ * HID / 4 / 256), blk, 0, stream>>>(
        (const float4*)part, (float4*)out);
}

// Round 11
// 594.855 us; speedup vs baseline: 1.0635x; 1.0635x over previous
//
#include <hip/hip_runtime.h>
#include <hip/hip_bf16.h>
#include <math.h>

#define HID     2560
#define D_INNER 8192
#define NG      32
#define D_SSM   4096
#define KCONV   4
#define HD      128
#define DS      64
#define LSEQ    1024
#define LC      64
#define NC      (LSEQ / LC)
#define NZ      4224          // z(4096) + dt(32) + D(32) + pad(64)
#define NBIG    12416         // qkv(8192) + NZ
#define EPS_RMS 1e-6f

// ---- gemm_big256 deep-pipeline params ----
#define BKT       32          // K per tile
#define NKT       240         // K' = 3*2560 -> 240 tiles of 32
#define GB_BLOCKS 196         // 49 n-tiles * 4 m-tiles

typedef short bf16x8 __attribute__((ext_vector_type(8)));
typedef float f32x4 __attribute__((ext_vector_type(4)));
typedef float f32x16 __attribute__((ext_vector_type(16)));

__device__ __forceinline__ float siluf(float x) { return x / (1.f + expf(-x)); }

__device__ __forceinline__ unsigned short f2bf(float x) {
    __hip_bfloat16 b = __float2bfloat16(x);
    return *reinterpret_cast<unsigned short*>(&b);
}
__device__ __forceinline__ float bf2f(unsigned short u) {
    union { unsigned int i; float f; } v;
    v.i = ((unsigned int)u) << 16;
    return v.f;
}

__device__ __forceinline__ void async16(const ushort* g, ushort* l) {
    __builtin_amdgcn_global_load_lds(
        (const __attribute__((address_space(1))) unsigned int*)g,
        (__attribute__((address_space(3))) unsigned int*)l, 16, 0, 0);
}

// counted-vmcnt gate: drain own ds_reads (lgkmcnt 0), leave VM staging loads
// in flight across the raw barrier (T4). Compile-time VM only.
template<int VM>
__device__ __forceinline__ void gate_barrier() {
    asm volatile("s_waitcnt vmcnt(%0) lgkmcnt(0)" :: "n"(VM) : "memory");
    __builtin_amdgcn_s_barrier();
    asm volatile("" ::: "memory");
}

__device__ __forceinline__ void cvt4(const float4& v, ushort4& h, ushort4& l) {
    h.x = f2bf(v.x); l.x = f2bf(v.x - bf2f(h.x));
    h.y = f2bf(v.y); l.y = f2bf(v.y - bf2f(h.y));
    h.z = f2bf(v.z); l.z = f2bf(v.z - bf2f(h.z));
    h.w = f2bf(v.w); l.w = f2bf(v.w - bf2f(h.w));
}

// ---------------- fused input-plane conversion (5 launches -> 1) -----------
#define N4_HS   (LSEQ * HID / 4)
#define N4_QKV  (D_INNER * HID / 4)
#define N4_Z    (D_SSM * HID / 4)
#define N4_BA   (NG * HID / 4)
__global__ __launch_bounds__(256)
void split_cvt_all(const float4* __restrict__ hs, const float4* __restrict__ wqkv,
                   const float4* __restrict__ wz, const float4* __restrict__ wb,
                   const float4* __restrict__ wa,
                   ushort4* __restrict__ hsH4, ushort4* __restrict__ hsL4,
                   ushort4* __restrict__ WH4, ushort4* __restrict__ WL4) {
    int i = blockIdx.x * 256 + threadIdx.x;
    const float4* src; ushort4* dh; ushort4* dl; int j;
    if (i < N4_HS)                          { j = i;                       src = hs;   dh = hsH4; dl = hsL4; }
    else if ((j = i - N4_HS) < N4_QKV)      {                              src = wqkv; dh = WH4;  dl = WL4; }
    else if ((j -= N4_QKV) < N4_Z)          { src = wz; dh = WH4 + N4_QKV;            dl = WL4 + N4_QKV; }
    else if ((j -= N4_Z) < N4_BA)           { src = wb; dh = WH4 + N4_QKV + N4_Z;     dl = WL4 + N4_QKV + N4_Z; }
    else                                    { j -= N4_BA;
                                              src = wa; dh = WH4 + N4_QKV + N4_Z + N4_BA;
                                                        dl = WL4 + N4_QKV + N4_Z + N4_BA; }
    float4 v = src[j];
    ushort4 h, l; cvt4(v, h, l);
    dh[j] = h; dl[j] = l;
}

// ---------------- big GEMM: 256x256, 8 waves (2x4), 32x32x16 MFMA ----------
// v3 (round 11): round-9's proven 8-wave 512-thread pipeline (2 waves/SIMD,
// 4 loads/stage, gates <8>/<8>/<4>/<0>) + the 32x32x16 MFMA validated for
// correctness by round-10 (absmax passed). Round-10's twin failures fixed:
//  * occupancy: back to 8 waves (round-10's 4-wave had 1 wave/SIMD, no TLP);
//  * swizzle: 32-row reads need S(r) with bit1 = (r>>1)&1 so that paired
//    lanes (l, l+32) — same row, chunks c and c^1 — land in disjoint bank
//    groups under half-wave phasing. S(r) = (((r>>1)&1)<<1)|((r>>2)&1),
//    applied on BOTH store (csw) and read (cxr). Round-10's S=(r>>1)&3 had
//    bit1=(r>>2)&1 -> 2-way conflict every cycle (measured 1.2e7).
// Wave tile 128x64 -> 4x2 frags of 32x32; MFMA cycles/kt: 155 -> 129.
__global__ __launch_bounds__(512, 2)
void gemm_big256(const ushort* __restrict__ Ah, const ushort* __restrict__ Al,
                 const ushort* __restrict__ Bh, const ushort* __restrict__ Bl,
                 float* __restrict__ xBC, float* __restrict__ zq)
{
    __shared__ ushort lds[4][2][256][32];

    const int tid  = threadIdx.x;
    const int lane = tid & 63, wv = tid >> 6;       // 8 waves

    int id = blockIdx.x;
    const int qx = GB_BLOCKS / 8, rx = GB_BLOCKS % 8;       // 24, 4
    int xcd = id & 7, lid = id >> 3;
    int sw  = (xcd < rx) ? (xcd * (qx + 1) + lid)
                         : (rx * (qx + 1) + (xcd - rx) * qx + lid);
    const int m0 = (sw & 3) << 8;
    const int n0 = (sw >> 2) << 8;

    // stage-side: linear LDS dest; source k-chunk pre-swizzled with S(row),
    // row = lane>>2 (mod 16):  S bits -> bit1=(lane>>3)&1, bit0=(lane>>4)&1.
    const int rb  = (wv << 4) + (lane >> 2);                 // row in 128-half
    const int csw = (((lane & 3) ^ ((((lane >> 3) & 1) << 1) | ((lane >> 4) & 1))) << 3);

    auto stage = [&](int kt, int slot) {
        int third = kt / 80;
        int kk = (kt - third * 80) * BKT;
        const ushort* Ap = (third == 2) ? Al : Ah;   // [Ah, Ah, Al]
        const ushort* Bp = (third == 1) ? Bl : Bh;   // [Bh, Bl, Bh]
        int cs = kk + csw;
        int ar0 = m0 + rb, ar1 = m0 + 128 + rb;
        int br0 = n0 + rb;        if (br0 > NBIG - 1) br0 = NBIG - 1;
        int br1 = n0 + 128 + rb;  if (br1 > NBIG - 1) br1 = NBIG - 1;
        ushort* dA = &lds[slot][0][wv << 4][0];      // wave-uniform base
        ushort* dB = &lds[slot][1][wv << 4][0];
        async16(Ap + (size_t)ar0 * HID + cs, dA);
        async16(Ap + (size_t)ar1 * HID + cs, dA + 128 * 32);
        async16(Bp + (size_t)br0 * HID + cs, dB);
        async16(Bp + (size_t)br1 * HID + cs, dB + 128 * 32);
    };

    // compute-side: 2x4 waves, per-wave 128x64, 4x2 frags of 32x32.
    const int wm  = (wv >> 2) << 7;                 // 0 / 128
    const int wn  = (wv & 3) << 6;                  // 0 / 64 / 128 / 192
    const int r31 = lane & 31;
    const int khi = lane >> 5;                      // k = khi*8 within 16-k
    const int cxr = (((lane >> 1) & 1) << 1) | ((lane >> 2) & 1);   // S(r31)

    f32x16 acc[4][2];
    #pragma unroll
    for (int i = 0; i < 4; i++)
        #pragma unroll
        for (int j = 0; j < 2; j++)
            acc[i][j] = (f32x16){0.f,0.f,0.f,0.f,0.f,0.f,0.f,0.f,
                                 0.f,0.f,0.f,0.f,0.f,0.f,0.f,0.f};

    auto compute = [&](int slot) {
        const ushort* sA = &lds[slot][0][0][0];
        const ushort* sB = &lds[slot][1][0][0];
        bf16x8 a[4][2], b[2][2];
        #pragma unroll
        for (int k0 = 0; k0 < 2; k0++) {
            int ph = ((k0 * 2 + khi) ^ cxr) << 3;
            #pragma unroll
            for (int f = 0; f < 4; f++)
                a[f][k0] = *(const bf16x8*)&sA[(wm + f * 32 + r31) * 32 + ph];
            #pragma unroll
            for (int f = 0; f < 2; f++)
                b[f][k0] = *(const bf16x8*)&sB[(wn + f * 32 + r31) * 32 + ph];
        }
        __builtin_amdgcn_s_setprio(1);
        #pragma unroll
        for (int fm = 0; fm < 4; fm++)
            #pragma unroll
            for (int fn = 0; fn < 2; fn++)
                #pragma unroll
                for (int k0 = 0; k0 < 2; k0++)
                    acc[fm][fn] = __builtin_amdgcn_mfma_f32_32x32x16_bf16(
                        a[fm][k0], b[fn][k0], acc[fm][fn], 0, 0, 0);
        __builtin_amdgcn_s_setprio(0);
    };

    // prologue: prefetch depth 3 (12 loads/wave in flight) — round-9 ladder
    stage(0, 0); stage(1, 1); stage(2, 2);

    #pragma unroll 4
    for (int kt = 0; kt < NKT - 4; kt++) {
        gate_barrier<8>();
        stage(kt + 3, (kt + 3) & 3);
        compute(kt & 3);
    }
    gate_barrier<8>(); stage(239, 3); compute(0);
    gate_barrier<8>(); compute(1);
    gate_barrier<4>(); compute(2);
    gate_barrier<0>(); compute(3);

    // ---- epilogue: 32x32 C/D layout (round-10 HW-validated), split cols ----
    const int rbase = (lane >> 5) << 2;     // 4*(lane>>5)
    #pragma unroll
    for (int fm = 0; fm < 4; fm++) {
        #pragma unroll
        for (int fn = 0; fn < 2; fn++) {
            int col = n0 + wn + fn * 32 + r31;
            if (col < 8192) {
                #pragma unroll
                for (int reg = 0; reg < 16; reg++) {
                    int row = m0 + wm + fm * 32 + (reg & 3) + 8 * (reg >> 2) + rbase;
                    xBC[(size_t)row * 8192 + col] = acc[fm][fn][reg];
                }
            } else if (col < NBIG) {
                #pragma unroll
                for (int reg = 0; reg < 16; reg++) {
                    int row = m0 + wm + fm * 32 + (reg & 3) + 8 * (reg >> 2) + rbase;
                    zq[(size_t)row * NZ + (col - 8192)] = acc[fm][fn][reg];
                }
            }
        }
    }
}

// ---------------- phase-2 fused: conv+SiLU | W_out cvt | dt_scan ------------
#define CONV_BLKS 2048
#define WOUT_BLKS 2560
#define DT_BLKS   NG
__global__ __launch_bounds__(1024)
void phase2_fused(const float4* __restrict__ xBC4, const float4* __restrict__ cw4,
                  float4* __restrict__ xconv4,
                  const float4* __restrict__ Wout_src,
                  ushort4* __restrict__ WoH4, ushort4* __restrict__ WoL4,
                  const float* __restrict__ zq,
                  const float* __restrict__ A_log, const float* __restrict__ dt_bias,
                  float* __restrict__ dt_soft, float* __restrict__ Sbuf,
                  float* __restrict__ Ebuf) {
    const int tid = threadIdx.x;
    if (blockIdx.x < CONV_BLKS) {
        int idx4 = blockIdx.x * 1024 + tid;
        int t  = idx4 >> 11;
        int c4 = idx4 & 2047;
        float4 w0 = cw4[c4 * 4 + 0], w1 = cw4[c4 * 4 + 1];
        float4 w2 = cw4[c4 * 4 + 2], w3 = cw4[c4 * 4 + 3];
        float4 acc = {0.f, 0.f, 0.f, 0.f};
        #pragma unroll
        for (int k = 0; k < KCONV; k++) {
            int tt = t - (KCONV - 1) + k;
            if (tt >= 0) {
                float4 x = xBC4[(size_t)tt * 2048 + c4];
                float t0 = (k == 0) ? w0.x : (k == 1) ? w0.y : (k == 2) ? w0.z : w0.w;
                float t1 = (k == 0) ? w1.x : (k == 1) ? w1.y : (k == 2) ? w1.z : w1.w;
                float t2 = (k == 0) ? w2.x : (k == 1) ? w2.y : (k == 2) ? w2.z : w2.w;
                float t3 = (k == 0) ? w3.x : (k == 1) ? w3.y : (k == 2) ? w3.z : w3.w;
                acc.x += x.x * t0; acc.y += x.y * t1;
                acc.z += x.z * t2; acc.w += x.w * t3;
            }
        }
        acc.x = siluf(acc.x); acc.y = siluf(acc.y);
        acc.z = siluf(acc.z); acc.w = siluf(acc.w);
        xconv4[idx4] = acc;
    } else if (blockIdx.x < CONV_BLKS + WOUT_BLKS) {
        int i = (blockIdx.x - CONV_BLKS) * 1024 + tid;
        float4 v = Wout_src[i];
        ushort4 h, l; cvt4(v, h, l);
        WoH4[i] = h; WoL4[i] = l;
    } else {
        const int g = blockIdx.x - (CONV_BLKS + WOUT_BLKS);
        const int t = tid;
        __shared__ float buf0[LSEQ], buf1[LSEQ];
        float dtr = zq[(size_t)t * NZ + D_SSM + g] + dt_bias[g];
        float dt = (dtr > 20.f) ? dtr : log1pf(expf(dtr));
        dt_soft[g * LSEQ + t] = dt;
        buf0[t] = dt;
        __syncthreads();
        float* src = buf0; float* dst = buf1;
        for (int off = 1; off < LSEQ; off <<= 1) {
            float v = src[t];
            if (t >= off) v += src[t - off];
            dst[t] = v;
            __syncthreads();
            float* tmp = src; src = dst; dst = tmp;
        }
        float A = -expf(A_log[g]);
        float S = A * src[t];
        Sbuf[g * LSEQ + t] = S;
        if ((t & (LC - 1)) == LC - 1) Ebuf[g * NC + (t >> 6)] = S;
    }
}

// ---------------- out GEMM: 256^2 tiles, split-K x6, DIRECT partial stores --
__global__ __launch_bounds__(512, 2)
void gemm_out_sk256(const ushort* __restrict__ Ah, const ushort* __restrict__ Al,
                    const ushort* __restrict__ Bh, const ushort* __restrict__ Bl,
                    float* __restrict__ P)
{
    constexpr int LDA = D_SSM;
    constexpr int KT3 = 128;

    __shared__ ushort lds[4][2][256][32];

    const int tid  = threadIdx.x;
    const int lane = tid & 63, wv = tid >> 6;

    const int bid = blockIdx.x;
    const int wid = (bid & 7) * 30 + (bid >> 3);
    const int m   = wid & 3;
    const int q   = wid >> 2;
    const int n   = q % 10;
    const int kz  = q / 10;
    const int m0  = m << 8, n0 = n << 8;
    const int kt0 = kz * 64;

    const int rb  = (wv << 4) + (lane >> 2);
    const int csw = (((lane & 3) ^ ((lane >> 3) & 3)) << 3);
    const int wm  = (wv >> 2) << 7;
    const int wn  = (wv & 3) << 6;
    const int fr  = lane & 15;
    const int ckr = (((lane >> 4) ^ ((lane >> 1) & 3)) << 3);
    const int rq  = (lane >> 4) << 2;

    auto stage = [&](int kt, int slot) {
        int third = kt / KT3;
        int kk = (kt - third * KT3) * BKT;
        const ushort* Ap = (third == 2) ? Al : Ah;
        const ushort* Bp = (third == 1) ? Bl : Bh;
        int cs = kk + csw;
        ushort* dA = &lds[slot][0][wv << 4][0];
        ushort* dB = &lds[slot][1][wv << 4][0];
        async16(Ap + (size_t)(m0 + rb) * LDA + cs, dA);
        async16(Ap + (size_t)(m0 + 128 + rb) * LDA + cs, dA + 128 * 32);
        async16(Bp + (size_t)(n0 + rb) * LDA + cs, dB);
        async16(Bp + (size_t)(n0 + 128 + rb) * LDA + cs, dB + 128 * 32);
    };

    f32x4 acc[8][4];
    #pragma unroll
    for (int i = 0; i < 8; i++)
        #pragma unroll
        for (int j = 0; j < 4; j++) acc[i][j] = (f32x4){0.f, 0.f, 0.f, 0.f};

    auto compute = [&](int slot) {
        const ushort* sA = &lds[slot][0][0][0];
        const ushort* sB = &lds[slot][1][0][0];
        bf16x8 a[8], b[4];
        #pragma unroll
        for (int mt = 0; mt < 8; mt++)
            a[mt] = *(const bf16x8*)&sA[(wm + mt * 16 + fr) * 32 + ckr];
        #pragma unroll
        for (int nt = 0; nt < 4; nt++)
            b[nt] = *(const bf16x8*)&sB[(wn + nt * 16 + fr) * 32 + ckr];
        __builtin_amdgcn_s_setprio(1);
        #pragma unroll
        for (int mt = 0; mt < 8; mt++)
            #pragma unroll
            for (int nt = 0; nt < 4; nt++)
                acc[mt][nt] = __builtin_amdgcn_mfma_f32_16x16x32_bf16(
                    a[mt], b[nt], acc[mt][nt], 0, 0, 0);
        __builtin_amdgcn_s_setprio(0);
    };

    stage(kt0 + 0, 0); stage(kt0 + 1, 1); stage(kt0 + 2, 2);
    #pragma unroll 4
    for (int i = 0; i < 60; i++) {
        gate_barrier<8>();
        stage(kt0 + i + 3, (i + 3) & 3);
        compute(i & 3);
    }
    gate_barrier<8>(); stage(kt0 + 63, 63 & 3); compute(60 & 3);
    gate_barrier<8>(); compute(61 & 3);
    gate_barrier<4>(); compute(62 & 3);
    gate_barrier<0>(); compute(63 & 3);

    float* dst = P + (size_t)kz * LSEQ * HID;
    #pragma unroll
    for (int mt = 0; mt < 8; mt++) {
        int row = m0 + wm + mt * 16 + rq;
        #pragma unroll
        for (int nt = 0; nt < 4; nt++) {
            int col = n0 + wn + nt * 16 + fr;
            #pragma unroll
            for (int r = 0; r < 4; r++)
                dst[(size_t)(row + r) * HID + col] = acc[mt][nt][r];
        }
    }
}

// ---------------- reduce the 6 split-K partials into out ----------------
__global__ __launch_bounds__(256)
void reduce6(const float4* __restrict__ P4, float4* __restrict__ out4) {
    const int N4 = LSEQ * HID / 4;       // 655,360
    int i = blockIdx.x * 256 + threadIdx.x;
    float4 s = P4[i];
    #pragma unroll
    for (int kz = 1; kz < 6; kz++) {
        float4 p = P4[(size_t)kz * N4 + i];
        s.x += p.x; s.y += p.y; s.z += p.z; s.w += p.w;
    }
    out4[i] = s;
}

// ---------------- S2: chunk states ----------------
__global__ __launch_bounds__(256)
void chunk_state(const float* __restrict__ xc, const float* __restrict__ dt_soft,
                 const float* __restrict__ Sbuf, const float* __restrict__ Ebuf,
                 float* __restrict__ Sc) {
    const int g = blockIdx.x, c = blockIdx.y;
    const int tid = threadIdx.x;
    const int t0 = c * LC;
    __shared__ __align__(16) float wB[LC][DS];
    __shared__ float Xs[LC][HD];
    __shared__ float sw[LC];

    if (tid < LC) {
        float Ec = Ebuf[g * NC + c];
        sw[tid] = expf(Ec - Sbuf[g * LSEQ + t0 + tid]) * dt_soft[g * LSEQ + t0 + tid];
    }
    __syncthreads();
    for (int i = tid; i < LC * DS; i += 256) {
        int r = i >> 6, s = i & 63;
        wB[r][s] = sw[r] * xc[(size_t)(t0 + r) * D_INNER + D_SSM + g * DS + s];
    }
    for (int i = tid; i < LC * HD; i += 256) {
        int r = i >> 7, h = i & 127;
        Xs[r][h] = xc[(size_t)(t0 + r) * D_INNER + g * HD + h];
    }
    __syncthreads();

    const int h = tid & 127, sh = (tid >> 7) * 32;
    float acc[32];
    #pragma unroll
    for (int j = 0; j < 32; j++) acc[j] = 0.f;
    for (int r = 0; r < LC; r++) {
        float xv = Xs[r][h];
        const float4* wrow = (const float4*)&wB[r][sh];
        #pragma unroll
        for (int q = 0; q < 8; q++) {
            float4 w4 = wrow[q];
            acc[4*q+0] += w4.x * xv;
            acc[4*q+1] += w4.y * xv;
            acc[4*q+2] += w4.z * xv;
            acc[4*q+3] += w4.w * xv;
        }
    }
    float* out = Sc + (size_t)(g * NC + c) * DS * HD;
    #pragma unroll
    for (int j = 0; j < 32; j++) out[(size_t)(sh + j) * HD + h] = acc[j];
}

// ---------------- S3: prefix over chunks ----------------
__global__ __launch_bounds__(256)
void chunk_prefix(const float* __restrict__ Sc, const float* __restrict__ Ebuf,
                  float* __restrict__ Hbuf) {
    const int g = blockIdx.y;
    const int e = blockIdx.x * 256 + threadIdx.x;
    float H = 0.f, Eprev = 0.f;
    for (int c = 0; c < NC; c++) {
        size_t base = (size_t)(g * NC + c) * DS * HD;
        Hbuf[base + e] = H;
        float Ec = Ebuf[g * NC + c];
        H = expf(Ec - Eprev) * H + Sc[base + e];
        Eprev = Ec;
    }
}

// ---------------- S4: per-chunk output + RMSNorm + SiLU(z), emits yg hi/lo ----
__global__ __launch_bounds__(256)
void chunk_output(const float* __restrict__ xc, const float* __restrict__ dt_soft,
                  const float* __restrict__ Sbuf, const float* __restrict__ Ebuf,
                  const float* __restrict__ Hbuf,
                  const float* __restrict__ zq, const float* __restrict__ norm_w,
                  ushort* __restrict__ ygH, ushort* __restrict__ ygL) {
    const int g = blockIdx.x, c = blockIdx.y;
    const int tid = threadIdx.x;
    const int t0 = c * LC;

    __shared__ __align__(16) float smem[4096 + 4096 + 8192];
    float* CT = smem;
    float* BW = smem + 4096;
    float* Xs = smem + 8192;
    float* red = smem;
    float* sscale = smem + 256;

    for (int i = tid; i < LC * DS; i += 256) {
        int t = i >> 6, s = i & 63;
        CT[s * LC + t] = xc[(size_t)(t0 + t) * D_INNER + D_SSM + NG * DS + g * DS + s];
        BW[t * DS + s] = xc[(size_t)(t0 + t) * D_INNER + D_SSM + g * DS + s];
    }
    for (int i = tid; i < LC * HD; i += 256) {
        int t = i >> 7, h = i & 127;
        Xs[t * HD + h] = xc[(size_t)(t0 + t) * D_INNER + g * HD + h];
    }
    __syncthreads();

    {
        const int t = tid & 63, tau0 = tid >> 6;
        float Greg[16];
        #pragma unroll
        for (int k = 0; k < 16; k++) Greg[k] = 0.f;
        for (int s = 0; s < DS; s++) {
            float cv = CT[s * LC + t];
            #pragma unroll
            for (int k = 0; k < 16; k++) Greg[k] += cv * BW[(tau0 + 4 * k) * DS + s];
        }
        __syncthreads();
        float St = Sbuf[g * LSEQ + t0 + t];
        #pragma unroll
        for (int k = 0; k < 16; k++) {
            int tau = tau0 + 4 * k;
            float w = 0.f;
            if (tau <= t)
                w = expf(St - Sbuf[g * LSEQ + t0 + tau]) *
                    dt_soft[g * LSEQ + t0 + tau] * Greg[k];
            BW[tau * LC + t] = w;
        }
    }
    __syncthreads();

    const int h = tid & 127, tb = (tid >> 7) * 32;
    float y[32], T[32];
    #pragma unroll
    for (int j = 0; j < 32; j++) { y[j] = 0.f; T[j] = 0.f; }

    for (int tau = 0; tau < LC; tau++) {
        float xv = Xs[tau * HD + h];
        const float4* wrow = (const float4*)&BW[tau * LC + tb];
        #pragma unroll
        for (int q = 0; q < 8; q++) {
            float4 w4 = wrow[q];
            y[4*q+0] += w4.x * xv;
            y[4*q+1] += w4.y * xv;
            y[4*q+2] += w4.z * xv;
            y[4*q+3] += w4.w * xv;
        }
    }
    {
        const float* Hg = Hbuf + (size_t)(g * NC + c) * DS * HD;
        for (int s = 0; s < DS; s++) {
            float Hv = Hg[(size_t)s * HD + h];
            const float* crow = &CT[s * LC + tb];
            #pragma unroll
            for (int j = 0; j < 32; j++) T[j] += crow[j] * Hv;
        }
    }
    float Eprev = (c > 0) ? Ebuf[g * NC + c - 1] : 0.f;
    #pragma unroll
    for (int j = 0; j < 32; j++) {
        int t = tb + j;
        float St = Sbuf[g * LSEQ + t0 + t];
        float Dv = zq[(size_t)(t0 + t) * NZ + D_SSM + NG + g];
        y[j] += expf(St - Eprev) * T[j] + Dv * Xs[t * HD + h];
    }
    __syncthreads();
    #pragma unroll
    for (int j = 0; j < 32; j++) Xs[(tb + j) * HD + h] = y[j];
    __syncthreads();

    {
        int t = tid >> 2, q = tid & 3;
        float p = 0.f;
        for (int i = 0; i < 32; i++) {
            float v = Xs[t * HD + q * 32 + i];
            p += v * v;
        }
        red[t * 4 + q] = p;
    }
    __syncthreads();
    if (tid < LC) {
        float s2 = red[tid*4] + red[tid*4+1] + red[tid*4+2] + red[tid*4+3];
        sscale[tid] = rsqrtf(s2 * (1.f / HD) + EPS_RMS);
    }
    __syncthreads();

    float nw = norm_w[h];
    #pragma unroll
    for (int j = 0; j < 32; j++) {
        int t = tb + j;
        float zv = zq[(size_t)(t0 + t) * NZ + g * HD + h];
        size_t idx = (size_t)(t0 + t) * D_SSM + g * HD + h;
        float val = y[j] * sscale[t] * nw * siluf(zv);
        unsigned short hb = f2bf(val);
        ygH[idx] = hb;
        ygL[idx] = f2bf(val - bf2f(hb));
    }
}

extern "C" void kernel_launch(void* const* d_in, const int* in_sizes, int n_in,
                              void* d_out, int out_size, void* d_ws, size_t ws_size,
                              hipStream_t stream) {
    const float* hs      = (const float*)d_in[0];
    const float* W_qkv   = (const float*)d_in[1];
    const float* W_z     = (const float*)d_in[2];
    const float* W_a     = (const float*)d_in[3];
    const float* W_b     = (const float*)d_in[4];
    const float* conv_w  = (const float*)d_in[5];
    const float* W_out   = (const float*)d_in[6];
    const float* norm_w  = (const float*)d_in[7];
    const float* A_log   = (const float*)d_in[8];
    const float* dt_bias = (const float*)d_in[9];
    float* out = (float*)d_out;

    float* ws      = (float*)d_ws;
    float* xBC     = ws;                                   // 8,388,608 f
    float* zq      = xBC + (size_t)LSEQ * D_INNER;         // 4,325,376 f
    float* dt_soft = zq + (size_t)LSEQ * NZ;               // 32768 f
    float* Sbuf    = dt_soft + (size_t)NG * LSEQ;          // 32768 f
    float* Ebuf    = Sbuf + (size_t)NG * LSEQ;             // 512 f
    ushort* hsH    = (ushort*)(Ebuf + 512);                // 2,621,440 us
    ushort* hsL    = hsH + (size_t)LSEQ * HID;
    ushort* WH     = hsL + (size_t)LSEQ * HID;             // NBIG*HID = 31,784,960 us
    ushort* WL     = WH + (size_t)NBIG * HID;
    // phase-2 overlay on WH/WL region (dead after gemm_big256):
    float* xconv   = (float*)WH;                           // 8,388,608 f
    float* Sc      = xconv + (size_t)LSEQ * D_INNER;       // 4,194,304 f
    float* Hbuf    = Sc + (size_t)NG * NC * DS * HD;       // 4,194,304 f
    ushort* ygH    = (ushort*)(Hbuf + (size_t)NG * NC * DS * HD);  // 4,194,304 us
    ushort* ygL    = ygH + (size_t)LSEQ * D_SSM;
    ushort* WoH    = ygL + (size_t)LSEQ * D_SSM;           // 10,485,760 us
    ushort* WoL    = WoH + (size_t)HID * D_SSM;
    // phase-3 overlay: split-K partials [6][1024][2560] f32 (15.7M f) in
    // xconv+Sc+Hbuf (16.8M f) — dead after chunk_output (round-6 audit).
    float* part    = xconv;

    // 1) all input planes in one kernel
    split_cvt_all<<<dim3(33440), dim3(256), 0, stream>>>(
        (const float4*)hs, (const float4*)W_qkv, (const float4*)W_z,
        (const float4*)W_b, (const float4*)W_a,
        (ushort4*)hsH, (ushort4*)hsL, (ushort4*)WH, (ushort4*)WL);

    // 2) merged projection GEMM: 196 blocks, 8-wave + 32x32x16 v3
    gemm_big256<<<dim3(GB_BLOCKS), dim3(512), 0, stream>>>(
        hsH, hsL, WH, WL, xBC, zq);

    // 3) conv+SiLU | W_out planes | dt-scan
    phase2_fused<<<dim3(CONV_BLKS + WOUT_BLKS + DT_BLKS), dim3(1024), 0, stream>>>(
        (const float4*)xBC, (const float4*)conv_w, (float4*)xconv,
        (const float4*)W_out, (ushort4*)WoH, (ushort4*)WoL,
        zq, A_log, dt_bias, dt_soft, Sbuf, Ebuf);

    dim3 blk(256);
    chunk_state<<<dim3(NG, NC), blk, 0, stream>>>(xconv, dt_soft, Sbuf, Ebuf, Sc);
    chunk_prefix<<<dim3(DS * HD / 256, NG), blk, 0, stream>>>(Sc, Ebuf, Hbuf);
    chunk_output<<<dim3(NG, NC), blk, 0, stream>>>(xconv, dt_soft, Sbuf, Ebuf,
                                                   Hbuf, zq, norm_w, ygH, ygL);

    // out = yg @ W_out^T: direct partial stores (no atomics), then reduce.
    gemm_out_sk256<<<dim3(240), dim3(512), 0, stream>>>(
        ygH, ygL, WoH, WoL, part);
    reduce6<<<dim3(LSEQ * HID / 4 / 256), blk, 0, stream>>>(
        (const float4*)part, (float4*)out);
}